// Round 7
// baseline (884.375 us; speedup 1.0000x reference)
//
#include <hip/hip_runtime.h>
#include <hip/hip_fp16.h>

#define N_NODES 20000
#define N_EDGES 320000
#define DIM 256
// H=8 heads, C=32 channels/head

typedef _Float16 f16;
typedef unsigned int u32;
typedef f16 f16x8 __attribute__((ext_vector_type(8)));
typedef f16 f16x4 __attribute__((ext_vector_type(4)));
typedef float f32x4 __attribute__((ext_vector_type(4)));

#define GLL16(gsrc, ldst) __builtin_amdgcn_global_load_lds( \
    (const u32 __attribute__((address_space(1)))*)(gsrc),   \
    (u32 __attribute__((address_space(3)))*)(ldst), 16, 0, 0)

// ---- prep: 5 weights f32 (K x N) -> f16 transposed (N x K); pack biases; zero deg ----
__global__ void prep_all(const float* __restrict__ Wq, const float* __restrict__ Wk,
                         const float* __restrict__ Wv, const float* __restrict__ Ws,
                         const float* __restrict__ We,
                         const float* __restrict__ bq, const float* __restrict__ bk,
                         const float* __restrict__ bv, const float* __restrict__ bs,
                         f16* __restrict__ wtbase, float* __restrict__ biasAll,
                         int* __restrict__ deg) {
    if (blockIdx.x < 1280) {
        int gid = blockIdx.x * 256 + threadIdx.x;
        int w = gid >> 16;            // 0..4 : q,k,v,s,e
        int idx = gid & 65535;
        int k = idx >> 8, n = idx & 255;
        const float* W = (w == 0) ? Wq : (w == 1) ? Wk : (w == 2) ? Wv : (w == 3) ? Ws : We;
        wtbase[w * 65536 + n * 256 + k] = (f16)W[k * 256 + n];
    } else if (blockIdx.x < 1284) {
        int i = (blockIdx.x - 1280) * 256 + threadIdx.x;  // 0..1023
        int y = i >> 8, col = i & 255;
        const float* b = (y == 0) ? bq : (y == 1) ? bk : (y == 2) ? bv : bs;
        biasAll[i] = b[col];
    } else {
        int i = (blockIdx.x - 1284) * 256 + threadIdx.x;
        if (i < N_NODES) deg[i] = 0;
    }
}

// ---- GEMM v6: persistent, full-K LDS weight, barrier-free steady state ----
// 256 blocks x 512 thr (8 waves), 1 block/CU (128 KB LDS = full 256x256 f16 WT).
// Stage WT once, one __syncthreads, then loop over output tiles (128 rows x 256
// cols, ~10/block) with NO barriers: per tile, convert current A regs (waits
// loads issued one tile earlier), issue next tile's 16 A-loads, prefetch the
// A-row index two tiles ahead, 128 MFMA from LDS, store. Waves free-run; each
// keeps ~16 KB in flight -> HBM streams.
// LDS: row r (0..255) x 32 slots of 16B; logical k-chunk kc at slot kc^(r&31)
// (pre-swizzled global source, linear LDS dest; matching XOR on ds_read ->
// 0 bank conflicts, verified R4/R6).
// EDGE=1: A row gathered via eids (full 1KB lines), ef stored SEQUENTIALLY in
// CSR-slot order (full lines). EDGE=0: outSel=blockIdx&3 (q,k,v,skip), clamp.
template<int EDGE>
__global__ __launch_bounds__(512, 2) void gemm_v6(
    const float* __restrict__ A, const f16* __restrict__ WTbase,
    const float* __restrict__ biasAll, const int* __restrict__ eids,
    f16* __restrict__ outF16, float* __restrict__ outF32)
{
    __shared__ __align__(16) char lds[131072];
    const int tid = threadIdx.x;
    const int wave = tid >> 6, lane = tid & 63;
    const int l16 = lane & 15, lg = lane >> 4;

    int outSel, x0, xStride, tilesX;
    if (EDGE) { outSel = 4; x0 = blockIdx.x; xStride = 256; tilesX = N_EDGES / 128; }
    else      { outSel = blockIdx.x & 3; x0 = blockIdx.x >> 2; xStride = 64; tilesX = (N_NODES + 127) / 128; }
    const f16* __restrict__ WT = WTbase + outSel * 65536;

    // ---- stage full weight (128 KB) into LDS: wave stages rows [wave*32,+32) ----
    {
        const int p = lane & 31, rofs = lane >> 5;
#pragma unroll
        for (int c = 0; c < 16; ++c) {
            const int row = wave * 32 + c * 2 + rofs;
            const f16* src = WT + row * 256 + ((p ^ (row & 31)) << 3);
            GLL16(src, &lds[(wave * 32 + c * 2) * 512]);   // lane l -> base + l*16
        }
    }

    float bias_[16];
    if (!EDGE) {
#pragma unroll
        for (int ct = 0; ct < 16; ++ct)
            bias_[ct] = biasAll[outSel * 256 + ct * 16 + l16];
    }

    const int slotBase = wave * 16 + l16;
    auto rowOf = [&](int x) -> int {
        const int slot = x * 128 + slotBase;
        if (EDGE) return eids[slot];
        return slot < N_NODES ? slot : N_NODES - 1;
    };

    f32x4 lo[8], hi[8];
#define ISSUE_A(r_) do {                                                       \
    const float* _ap = A + (size_t)(r_) * DIM + lg * 8;                        \
    _Pragma("unroll")                                                          \
    for (int _ks = 0; _ks < 8; ++_ks) {                                        \
        lo[_ks] = *(const f32x4*)(_ap + _ks * 32);                             \
        hi[_ks] = *(const f32x4*)(_ap + _ks * 32 + 4);                         \
    } } while (0)

    // prologue: loads for tile x0 in flight before the stage barrier
    {
        const int r0 = rowOf(x0);
        ISSUE_A(r0);
    }
    int rNext = (x0 + xStride < tilesX) ? rowOf(x0 + xStride) : 0;

    __syncthreads();   // stage drained; tile-x0 A loads already in flight

    for (int x = x0; x < tilesX; x += xStride) {
        // convert this tile's A (waits on its loads)
        f16x8 afr[8];
#pragma unroll
        for (int ks = 0; ks < 8; ++ks) {
#pragma unroll
            for (int j = 0; j < 4; ++j) {
                afr[ks][j]     = (f16)lo[ks][j];
                afr[ks][4 + j] = (f16)hi[ks][j];
            }
        }
        // issue next tile's A loads; prefetch the row index two tiles ahead
        if (x + xStride < tilesX) ISSUE_A(rNext);
        const int rAfter = (x + 2 * xStride < tilesX) ? rowOf(x + 2 * xStride) : 0;

        f32x4 acc[16];
#pragma unroll
        for (int c = 0; c < 16; ++c) acc[c] = (f32x4){0.f, 0.f, 0.f, 0.f};

#pragma unroll
        for (int ks = 0; ks < 8; ++ks) {
#pragma unroll
            for (int ct = 0; ct < 16; ++ct) {
                const int nrel = ct * 16 + l16;
                const int kc = ks * 4 + lg;
                f16x8 b = *(const f16x8*)(lds + nrel * 512 + ((kc ^ (nrel & 31)) << 4));
                acc[ct] = __builtin_amdgcn_mfma_f32_16x16x32_f16(afr[ks], b, acc[ct], 0, 0, 0);
            }
        }
        rNext = rAfter;

        // store: col = ct*16+l16, row = x*128 + wave*16 + lg*4 + i
#pragma unroll
        for (int ct = 0; ct < 16; ++ct) {
            const int col = ct * 16 + l16;
#pragma unroll
            for (int i = 0; i < 4; ++i) {
                const int row = x * 128 + wave * 16 + lg * 4 + i;
                if (EDGE) {
                    outF16[(size_t)row * 256 + col] = (f16)acc[ct][i];
                } else if (row < N_NODES) {
                    const float val = acc[ct][i] + bias_[ct];
                    if (outSel < 3)
                        (outF16 + (size_t)outSel * N_NODES * 256)[(size_t)row * 256 + col] = (f16)val;
                    else
                        outF32[(size_t)row * 256 + col] = val;
                }
            }
        }
    }
#undef ISSUE_A
}

// ---- CSR build (by dst) ----
__global__ void count_deg(const int* __restrict__ dst, int* __restrict__ deg) {
    int e = blockIdx.x * blockDim.x + threadIdx.x;
    if (e < N_EDGES) atomicAdd(&deg[dst[e]], 1);
}

__global__ __launch_bounds__(1024) void scan_deg(const int* __restrict__ deg,
                                                 int* __restrict__ rowptr,
                                                 int* __restrict__ cursor) {
    __shared__ int part[1024];
    const int t = threadIdx.x;
    const int CH = (N_NODES + 1023) / 1024; // 20
    const int base = t * CH;
    int s = 0;
    for (int i = 0; i < CH; ++i) { int n = base + i; if (n < N_NODES) s += deg[n]; }
    part[t] = s;
    __syncthreads();
    for (int off = 1; off < 1024; off <<= 1) {
        int v = (t >= off) ? part[t - off] : 0;
        __syncthreads();
        part[t] += v;
        __syncthreads();
    }
    int run = (t == 0) ? 0 : part[t - 1];
    for (int i = 0; i < CH; ++i) {
        int n = base + i;
        if (n < N_NODES) { int dn = deg[n]; rowptr[n] = run; cursor[n] = run; run += dn; }
    }
    if (t == 1023) rowptr[N_NODES] = part[1023]; // == E
}

__global__ void scatter_edges(const int* __restrict__ src, const int* __restrict__ dst,
                              int* __restrict__ cursor,
                              int* __restrict__ eids, int* __restrict__ srcs) {
    int e = blockIdx.x * blockDim.x + threadIdx.x;
    if (e < N_EDGES) {
        int p = atomicAdd(&cursor[dst[e]], 1);
        eids[p] = e;          // CSR slot -> edge id (edge-GEMM A gather)
        srcs[p] = src[e];     // CSR-ordered source ids
    }
}

// ---- fused softmax + aggregate: one wave per dst node ----
// ef and srcs are CSR-ordered -> fully sequential; k/v gathers are L2/L3-resident.
// lane l handles channels [4l, 4l+4); head h = l/8 spans lanes [8h, 8h+8).
__global__ __launch_bounds__(256) void aggregate(
    const f16* __restrict__ qf, const f16* __restrict__ kf, const f16* __restrict__ vf,
    const f16* __restrict__ ef, const int* __restrict__ srcs,
    const int* __restrict__ rowptr, float* __restrict__ out)
{
    const int wave = threadIdx.x >> 6;
    const int lane = threadIdx.x & 63;
    const int node = blockIdx.x * 4 + wave;
    if (node >= N_NODES) return;
    const int c0 = lane * 4;

    f32x4 qv;
    {
        f16x4 qh = *(const f16x4*)(qf + (size_t)node * 256 + c0);
        qv = (f32x4){(float)qh[0], (float)qh[1], (float)qh[2], (float)qh[3]};
    }
    float acc0 = 0.f, acc1 = 0.f, acc2 = 0.f, acc3 = 0.f, den = 0.f;
    const int beg = rowptr[node], end = rowptr[node + 1];

#define BODY(eh, kh, vh) {                                                      \
        const float _e0 = (float)(eh)[0], _e1 = (float)(eh)[1];                 \
        const float _e2 = (float)(eh)[2], _e3 = (float)(eh)[3];                 \
        float _d = qv[0] * ((float)(kh)[0] + _e0) + qv[1] * ((float)(kh)[1] + _e1) \
                 + qv[2] * ((float)(kh)[2] + _e2) + qv[3] * ((float)(kh)[3] + _e3); \
        _d += __shfl_xor(_d, 1);                                                \
        _d += __shfl_xor(_d, 2);                                                \
        _d += __shfl_xor(_d, 4);                                                \
        const float _w = __expf(_d * 0.1767766952966369f);                      \
        den += _w;                                                              \
        acc0 += _w * ((float)(vh)[0] + _e0);                                    \
        acc1 += _w * ((float)(vh)[1] + _e1);                                    \
        acc2 += _w * ((float)(vh)[2] + _e2);                                    \
        acc3 += _w * ((float)(vh)[3] + _e3);                                    \
    }

    int idx = beg;
    for (; idx + 4 <= end; idx += 4) {
        const int s0 = srcs[idx], s1 = srcs[idx + 1], s2 = srcs[idx + 2], s3 = srcs[idx + 3];
        f16x4 ea0 = *(const f16x4*)(ef + (size_t)(idx + 0) * 256 + c0);
        f16x4 ea1 = *(const f16x4*)(ef + (size_t)(idx + 1) * 256 + c0);
        f16x4 ea2 = *(const f16x4*)(ef + (size_t)(idx + 2) * 256 + c0);
        f16x4 ea3 = *(const f16x4*)(ef + (size_t)(idx + 3) * 256 + c0);
        f16x4 ka0 = *(const f16x4*)(kf + (size_t)s0 * 256 + c0);
        f16x4 ka1 = *(const f16x4*)(kf + (size_t)s1 * 256 + c0);
        f16x4 ka2 = *(const f16x4*)(kf + (size_t)s2 * 256 + c0);
        f16x4 ka3 = *(const f16x4*)(kf + (size_t)s3 * 256 + c0);
        f16x4 va0 = *(const f16x4*)(vf + (size_t)s0 * 256 + c0);
        f16x4 va1 = *(const f16x4*)(vf + (size_t)s1 * 256 + c0);
        f16x4 va2 = *(const f16x4*)(vf + (size_t)s2 * 256 + c0);
        f16x4 va3 = *(const f16x4*)(vf + (size_t)s3 * 256 + c0);
        BODY(ea0, ka0, va0); BODY(ea1, ka1, va1); BODY(ea2, ka2, va2); BODY(ea3, ka3, va3);
    }
    for (; idx < end; ++idx) {
        const int s = srcs[idx];
        f16x4 eh1 = *(const f16x4*)(ef + (size_t)idx * 256 + c0);
        f16x4 kh1 = *(const f16x4*)(kf + (size_t)s * 256 + c0);
        f16x4 vh1 = *(const f16x4*)(vf + (size_t)s * 256 + c0);
        BODY(eh1, kh1, vh1);
    }
#undef BODY

    const float inv = 1.0f / (den + 1e-16f);
    const size_t ob = (size_t)node * 256 + c0;
    f32x4 o = *(f32x4*)(out + ob);              // holds skip from gemm_v6 outSel==3
    o[0] += acc0 * inv; o[1] += acc1 * inv; o[2] += acc2 * inv; o[3] += acc3 * inv;
    *(f32x4*)(out + ob) = o;
}

extern "C" void kernel_launch(void* const* d_in, const int* in_sizes, int n_in,
                              void* d_out, int out_size, void* d_ws, size_t ws_size,
                              hipStream_t stream) {
    const float* x   = (const float*)d_in[0];
    const int*   ei  = (const int*)d_in[1];     // [0..E): src, [E..2E): dst
    const float* ea  = (const float*)d_in[2];
    const float* Wq  = (const float*)d_in[3];
    const float* bq  = (const float*)d_in[4];
    const float* Wk  = (const float*)d_in[5];
    const float* bk  = (const float*)d_in[6];
    const float* Wv  = (const float*)d_in[7];
    const float* bv  = (const float*)d_in[8];
    const float* We  = (const float*)d_in[9];
    const float* Ws  = (const float*)d_in[10];
    const float* bs  = (const float*)d_in[11];
    float* out = (float*)d_out;

    const int* srcArr = ei;
    const int* dstArr = ei + N_EDGES;

    // workspace layout
    char* w = (char*)d_ws;
    size_t off = 0;
    f16* wtbase = (f16*)(w + off); off += 5 * 65536 * 2;            // q,k,v,s,e transposed
    f16* qf = (f16*)(w + off); off += (size_t)N_NODES * 256 * 2;
    f16* kf = (f16*)(w + off); off += (size_t)N_NODES * 256 * 2;
    f16* vf = (f16*)(w + off); off += (size_t)N_NODES * 256 * 2;
    f16* ef = (f16*)(w + off); off += (size_t)N_EDGES * 256 * 2;    // CSR-slot order
    int* deg    = (int*)(w + off); off += 80016;
    int* rowptr = (int*)(w + off); off += 80016;
    int* cursor = (int*)(w + off); off += 80016;
    int* eids   = (int*)(w + off); off += (size_t)N_EDGES * 4;      // CSR slot -> edge id
    int* srcs   = (int*)(w + off); off += (size_t)N_EDGES * 4;      // CSR-slot order
    float* biasAll = (float*)(w + off); off += 4 * 256 * 4;
    (void)ws_size; (void)n_in; (void)in_sizes; (void)out_size;

    // prep: weight transpose + bias pack + deg zero (one launch)
    prep_all<<<1284 + (N_NODES + 255) / 256, 256, 0, stream>>>(
        Wq, Wk, Wv, Ws, We, bq, bk, bv, bs, wtbase, biasAll, deg);

    // node GEMM (only needs wtbase/biasAll)
    gemm_v6<0><<<256, 512, 0, stream>>>(x, wtbase, biasAll, nullptr, qf, out);

    // CSR build (edge GEMM consumes eids for its A gather)
    count_deg<<<(N_EDGES + 255) / 256, 256, 0, stream>>>(dstArr, deg);
    scan_deg<<<1, 1024, 0, stream>>>(deg, rowptr, cursor);
    scatter_edges<<<(N_EDGES + 255) / 256, 256, 0, stream>>>(srcArr, dstArr, cursor, eids, srcs);

    // edge GEMM: persistent 256 blocks, A gathered via eids, ef stored CSR-sequential
    gemm_v6<1><<<256, 512, 0, stream>>>(ea, wtbase, nullptr, eids, ef, nullptr);

    // fused softmax + aggregation, one wave per node
    aggregate<<<N_NODES / 4, 256, 0, stream>>>(qf, kf, vf, ef, srcs, rowptr, out);
}

// Round 9
// 449.693 us; speedup vs baseline: 1.9666x; 1.9666x over previous
//
#include <hip/hip_runtime.h>
#include <hip/hip_fp16.h>

#define N_NODES 20000
#define N_EDGES 320000
#define DIM 256
// H=8 heads, C=32 channels/head

typedef _Float16 f16;
typedef unsigned int u32;
typedef f16 f16x8 __attribute__((ext_vector_type(8)));
typedef f16 f16x4 __attribute__((ext_vector_type(4)));
typedef float f32x4 __attribute__((ext_vector_type(4)));

#define GLL16(gsrc, ldst) __builtin_amdgcn_global_load_lds( \
    (const u32 __attribute__((address_space(1)))*)(gsrc),   \
    (u32 __attribute__((address_space(3)))*)(ldst), 16, 0, 0)

// ---- prep: weights f32 (K x N) -> f16 transposed (N x K); We f16 row-major;
//      pack biases; zero deg ----
__global__ void prep_all(const float* __restrict__ Wq, const float* __restrict__ Wk,
                         const float* __restrict__ Wv, const float* __restrict__ Ws,
                         const float* __restrict__ We,
                         const float* __restrict__ bq, const float* __restrict__ bk,
                         const float* __restrict__ bv, const float* __restrict__ bs,
                         f16* __restrict__ wtbase, f16* __restrict__ wef16,
                         float* __restrict__ biasAll, int* __restrict__ deg) {
    if (blockIdx.x < 1280) {
        int gid = blockIdx.x * 256 + threadIdx.x;
        int w = gid >> 16;            // 0..4 : q,k,v,s,e
        int idx = gid & 65535;
        int k = idx >> 8, n = idx & 255;
        const float* W = (w == 0) ? Wq : (w == 1) ? Wk : (w == 2) ? Wv : (w == 3) ? Ws : We;
        wtbase[w * 65536 + n * 256 + k] = (f16)W[k * 256 + n];
    } else if (blockIdx.x < 1536) {
        int idx = (blockIdx.x - 1280) * 256 + threadIdx.x;  // 0..65535
        wef16[idx] = (f16)We[idx];                          // row-major [d][hc]
    } else if (blockIdx.x < 1540) {
        int i = (blockIdx.x - 1536) * 256 + threadIdx.x;    // 0..1023
        int y = i >> 8, col = i & 255;
        const float* b = (y == 0) ? bq : (y == 1) ? bk : (y == 2) ? bv : bs;
        biasAll[i] = b[col];
    } else {
        int i = (blockIdx.x - 1540) * 256 + threadIdx.x;
        if (i < N_NODES) deg[i] = 0;
    }
}

// ---- node GEMM (R4-proven): q,k,v (f16) + skip (f32), grid (157, 8) ----
__global__ __launch_bounds__(512, 4) void gemm_qkvs(
    const float* __restrict__ A, const f16* __restrict__ WTbase,
    const float* __restrict__ biasAll,
    f16* __restrict__ outF16, float* __restrict__ outF32)
{
    __shared__ __align__(16) char lds[65536];
    const int tid = threadIdx.x;
    const int wave = tid >> 6, lane = tid & 63;
    const int l16 = lane & 15, lg = lane >> 4;
    const int y = blockIdx.y;
    const int outSel = y >> 1, colHalf = y & 1;
    const f16* __restrict__ WT = WTbase + outSel * 65536 + colHalf * 128 * 256;
    const int rowBase = blockIdx.x * 128 + wave * 16;

    const int slot = rowBase + l16;
    const int arow = (slot < N_NODES) ? slot : N_NODES - 1;
    const float* ap = A + (size_t)arow * DIM;
    f32x4 lo[8], hi[8];
#pragma unroll
    for (int ks = 0; ks < 8; ++ks) {
        lo[ks] = *(const f32x4*)(ap + ks * 32 + lg * 8);
        hi[ks] = *(const f32x4*)(ap + ks * 32 + lg * 8 + 4);
    }
    {
        const int p = lane & 31;
#pragma unroll
        for (int r = 0; r < 8; ++r) {
            const int nrel = wave * 16 + r * 2 + (lane >> 5);
            const f16* src = WT + nrel * 256 + (p ^ (nrel & 31)) * 8;
            GLL16(src, &lds[(wave * 16 + r * 2) * 512]);
        }
    }
    f16x8 afr[8];
#pragma unroll
    for (int ks = 0; ks < 8; ++ks) {
#pragma unroll
        for (int j = 0; j < 4; ++j) {
            afr[ks][j]     = (f16)lo[ks][j];
            afr[ks][4 + j] = (f16)hi[ks][j];
        }
    }
    f32x4 acc[8];
#pragma unroll
    for (int c = 0; c < 8; ++c) acc[c] = (f32x4){0.f, 0.f, 0.f, 0.f};

    __syncthreads();

#pragma unroll
    for (int ks = 0; ks < 8; ++ks) {
#pragma unroll
        for (int ct = 0; ct < 8; ++ct) {
            const int nrel = ct * 16 + l16;
            f16x8 b = *(const f16x8*)(lds + nrel * 512 + (((ks * 4 + lg) ^ (nrel & 31)) * 16));
            acc[ct] = __builtin_amdgcn_mfma_f32_16x16x32_f16(afr[ks], b, acc[ct], 0, 0, 0);
        }
    }
#pragma unroll
    for (int ct = 0; ct < 8; ++ct) {
        const int col = colHalf * 128 + ct * 16 + l16;
        const float bv = biasAll[outSel * 256 + col];
#pragma unroll
        for (int i = 0; i < 4; ++i) {
            const int row = rowBase + lg * 4 + i;
            if (row < N_NODES) {
                const float val = acc[ct][i] + bv;
                if (outSel < 3)
                    (outF16 + (size_t)outSel * N_NODES * 256)[(size_t)row * 256 + col] = (f16)val;
                else
                    outF32[(size_t)row * 256 + col] = val;
            }
        }
    }
}

// ---- G GEMM: G[i,h,d] = sum_c We[d, h*32+c] * q[i, h*32+c]  (f16 out) ----
// grid (ceil(N/64), 8 heads), 256 thr = 4 waves; K=32 single MFMA step.
__global__ __launch_bounds__(256, 4) void gemm_g(
    const f16* __restrict__ qf, const f16* __restrict__ wef16, f16* __restrict__ G)
{
    const int tid = threadIdx.x;
    const int wave = tid >> 6, lane = tid & 63;
    const int l16 = lane & 15, lg = lane >> 4;
    const int h = blockIdx.y;
    const int rowBase = blockIdx.x * 64 + wave * 16;

    int arow = rowBase + l16;
    if (arow >= N_NODES) arow = N_NODES - 1;
    f16x8 a = *(const f16x8*)(qf + (size_t)arow * 256 + h * 32 + lg * 8);

    f32x4 acc[16];
#pragma unroll
    for (int c = 0; c < 16; ++c) acc[c] = (f32x4){0.f, 0.f, 0.f, 0.f};
#pragma unroll
    for (int ct = 0; ct < 16; ++ct) {
        f16x8 b = *(const f16x8*)(wef16 + (size_t)(ct * 16 + l16) * 256 + h * 32 + lg * 8);
        acc[ct] = __builtin_amdgcn_mfma_f32_16x16x32_f16(a, b, acc[ct], 0, 0, 0);
    }
#pragma unroll
    for (int ct = 0; ct < 16; ++ct) {
        const int d = ct * 16 + l16;
#pragma unroll
        for (int i = 0; i < 4; ++i) {
            const int row = rowBase + lg * 4 + i;
            if (row < N_NODES)
                G[(size_t)row * 2048 + h * 256 + d] = (f16)acc[ct][i];
        }
    }
}

// ---- CSR build (by dst) ----
__global__ void count_deg(const int* __restrict__ dst, int* __restrict__ deg) {
    int e = blockIdx.x * blockDim.x + threadIdx.x;
    if (e < N_EDGES) atomicAdd(&deg[dst[e]], 1);
}

__global__ __launch_bounds__(1024) void scan_deg(const int* __restrict__ deg,
                                                 int* __restrict__ rowptr,
                                                 int* __restrict__ cursor) {
    __shared__ int part[1024];
    const int t = threadIdx.x;
    const int CH = (N_NODES + 1023) / 1024; // 20
    const int base = t * CH;
    int s = 0;
    for (int i = 0; i < CH; ++i) { int n = base + i; if (n < N_NODES) s += deg[n]; }
    part[t] = s;
    __syncthreads();
    for (int off = 1; off < 1024; off <<= 1) {
        int v = (t >= off) ? part[t - off] : 0;
        __syncthreads();
        part[t] += v;
        __syncthreads();
    }
    int run = (t == 0) ? 0 : part[t - 1];
    for (int i = 0; i < CH; ++i) {
        int n = base + i;
        if (n < N_NODES) { int dn = deg[n]; rowptr[n] = run; cursor[n] = run; run += dn; }
    }
    if (t == 1023) rowptr[N_NODES] = part[1023]; // == E
}

__global__ void scatter_edges(const int* __restrict__ src, const int* __restrict__ dst,
                              int* __restrict__ cursor,
                              int* __restrict__ eids, int* __restrict__ srcs) {
    int e = blockIdx.x * blockDim.x + threadIdx.x;
    if (e < N_EDGES) {
        int p = atomicAdd(&cursor[dst[e]], 1);
        eids[p] = e;          // CSR slot -> edge id (for ea gather)
        srcs[p] = src[e];     // CSR-ordered source ids
    }
}

// ---- fused attention aggregate: one wave per dst node ----
// lane l: head h=l>>3, sublane j=l&7; owns q/k/v channels c0=l*4 (=h*32+j*4) and
// d-slices {m*32+j*4 .. +4} of the 256-d attr space.
// Per edge: p = ea.G[h] + q.k (8-lane reduce); al = exp(p/sqrt(32));
// den += al; va += al*v; z_h[m] += al*e_m  (reuses the e_m loads from the dot).
// End: out += va/den; G[node][h][:] OVERWRITTEN with zhat = z/den (f16, bounded).
// Safe: each wave reads only its node's G rows before overwriting them; gemm_g
// fully rewrites G every launch -> replay-deterministic.
__global__ __launch_bounds__(256) void aggregate3(
    const f16* __restrict__ qf, const f16* __restrict__ kf, const f16* __restrict__ vf,
    f16* __restrict__ G, const float* __restrict__ ea,
    const int* __restrict__ eids, const int* __restrict__ srcs,
    const int* __restrict__ rowptr, float* __restrict__ out)
{
    const int wave = threadIdx.x >> 6;
    const int lane = threadIdx.x & 63;
    const int node = blockIdx.x * 4 + wave;
    if (node >= N_NODES) return;
    const int h = lane >> 3, j = lane & 7;
    const int c0 = lane * 4;

    f32x4 qv;
    {
        f16x4 qh = *(const f16x4*)(qf + (size_t)node * 256 + c0);
        qv = (f32x4){(float)qh[0], (float)qh[1], (float)qh[2], (float)qh[3]};
    }
    f32x4 ga[8];
#pragma unroll
    for (int m = 0; m < 8; ++m) {
        f16x4 gh = *(const f16x4*)(G + (size_t)node * 2048 + h * 256 + m * 32 + j * 4);
        ga[m] = (f32x4){(float)gh[0], (float)gh[1], (float)gh[2], (float)gh[3]};
    }

    f32x4 z[8];
#pragma unroll
    for (int m = 0; m < 8; ++m) z[m] = (f32x4){0.f, 0.f, 0.f, 0.f};
    f32x4 va = (f32x4){0.f, 0.f, 0.f, 0.f};
    float den = 0.f;
    const int beg = rowptr[node], end = rowptr[node + 1];

    int eid = 0, src = 0;
    if (beg < end) { eid = eids[beg]; src = srcs[beg]; }
    for (int idx = beg; idx < end; ++idx) {
        const int eidN = (idx + 1 < end) ? eids[idx + 1] : 0;
        const int srcN = (idx + 1 < end) ? srcs[idx + 1] : 0;
        const float* ep = ea + (size_t)eid * 256 + j * 4;
        f32x4 e0 = *(const f32x4*)(ep + 0 * 32);
        f32x4 e1 = *(const f32x4*)(ep + 1 * 32);
        f32x4 e2 = *(const f32x4*)(ep + 2 * 32);
        f32x4 e3 = *(const f32x4*)(ep + 3 * 32);
        f32x4 e4 = *(const f32x4*)(ep + 4 * 32);
        f32x4 e5 = *(const f32x4*)(ep + 5 * 32);
        f32x4 e6 = *(const f32x4*)(ep + 6 * 32);
        f32x4 e7 = *(const f32x4*)(ep + 7 * 32);
        f16x4 kh = *(const f16x4*)(kf + (size_t)src * 256 + c0);
        f16x4 vh = *(const f16x4*)(vf + (size_t)src * 256 + c0);

        float p = 0.f;
#define DOT4(ev, m_) p += (ev)[0]*ga[m_][0] + (ev)[1]*ga[m_][1] + (ev)[2]*ga[m_][2] + (ev)[3]*ga[m_][3]
        DOT4(e0, 0); DOT4(e1, 1); DOT4(e2, 2); DOT4(e3, 3);
        DOT4(e4, 4); DOT4(e5, 5); DOT4(e6, 6); DOT4(e7, 7);
#undef DOT4
        p += qv[0]*(float)kh[0] + qv[1]*(float)kh[1] + qv[2]*(float)kh[2] + qv[3]*(float)kh[3];
        p += __shfl_xor(p, 1);
        p += __shfl_xor(p, 2);
        p += __shfl_xor(p, 4);
        const float al = __expf(p * 0.1767766952966369f);  // 1/sqrt(32)
        den += al;
        va[0] += al * (float)vh[0]; va[1] += al * (float)vh[1];
        va[2] += al * (float)vh[2]; va[3] += al * (float)vh[3];
#define ZACC(ev, m_) { z[m_][0] += al*(ev)[0]; z[m_][1] += al*(ev)[1]; z[m_][2] += al*(ev)[2]; z[m_][3] += al*(ev)[3]; }
        ZACC(e0, 0); ZACC(e1, 1); ZACC(e2, 2); ZACC(e3, 3);
        ZACC(e4, 4); ZACC(e5, 5); ZACC(e6, 6); ZACC(e7, 7);
#undef ZACC
        eid = eidN; src = srcN;
    }

    const float inv = 1.0f / (den + 1e-16f);
    const size_t ob = (size_t)node * 256 + c0;
    f32x4 o = *(f32x4*)(out + ob);       // skip from gemm_qkvs outSel==3
    o[0] += va[0] * inv; o[1] += va[1] * inv; o[2] += va[2] * inv; o[3] += va[3] * inv;
    *(f32x4*)(out + ob) = o;
#pragma unroll
    for (int m = 0; m < 8; ++m) {
        f16x4 zh;
        zh[0] = (f16)(z[m][0] * inv); zh[1] = (f16)(z[m][1] * inv);
        zh[2] = (f16)(z[m][2] * inv); zh[3] = (f16)(z[m][3] * inv);
        *(f16x4*)(G + (size_t)node * 2048 + h * 256 + m * 32 + j * 4) = zh;
    }
}

// ---- Z GEMM (per-head): out[i, h*32+c] += sum_d zhat[i,h,d] * We[d, h*32+c] ----
// grid (157, 8 heads), 512 thr = 8 waves, wave: 16 rows x 32 cols; K=256.
// A = zhat rows (f16, stride 2048); B = We^T rows for head h (16 KB, L2-hot).
__global__ __launch_bounds__(512, 4) void gemm_z2(
    const f16* __restrict__ zf, const f16* __restrict__ WTe, float* __restrict__ out)
{
    const int tid = threadIdx.x;
    const int wave = tid >> 6, lane = tid & 63;
    const int l16 = lane & 15, lg = lane >> 4;
    const int h = blockIdx.y;
    const int rowBase = blockIdx.x * 128 + wave * 16;

    int arow = rowBase + l16;
    if (arow >= N_NODES) arow = N_NODES - 1;
    const f16* ap = zf + (size_t)arow * 2048 + h * 256 + lg * 8;

    f32x4 acc[2];
    acc[0] = (f32x4){0.f, 0.f, 0.f, 0.f};
    acc[1] = (f32x4){0.f, 0.f, 0.f, 0.f};
#pragma unroll
    for (int ks = 0; ks < 8; ++ks) {
        f16x8 a = *(const f16x8*)(ap + ks * 32);
#pragma unroll
        for (int ct = 0; ct < 2; ++ct) {
            f16x8 b = *(const f16x8*)(WTe + (size_t)(h * 32 + ct * 16 + l16) * 256 + ks * 32 + lg * 8);
            acc[ct] = __builtin_amdgcn_mfma_f32_16x16x32_f16(a, b, acc[ct], 0, 0, 0);
        }
    }
#pragma unroll
    for (int ct = 0; ct < 2; ++ct) {
        const int col = h * 32 + ct * 16 + l16;
#pragma unroll
        for (int i = 0; i < 4; ++i) {
            const int row = rowBase + lg * 4 + i;
            if (row < N_NODES)
                out[(size_t)row * 256 + col] += acc[ct][i];
        }
    }
}

extern "C" void kernel_launch(void* const* d_in, const int* in_sizes, int n_in,
                              void* d_out, int out_size, void* d_ws, size_t ws_size,
                              hipStream_t stream) {
    const float* x   = (const float*)d_in[0];
    const int*   ei  = (const int*)d_in[1];     // [0..E): src, [E..2E): dst
    const float* ea  = (const float*)d_in[2];
    const float* Wq  = (const float*)d_in[3];
    const float* bq  = (const float*)d_in[4];
    const float* Wk  = (const float*)d_in[5];
    const float* bk  = (const float*)d_in[6];
    const float* Wv  = (const float*)d_in[7];
    const float* bv  = (const float*)d_in[8];
    const float* We  = (const float*)d_in[9];
    const float* Ws  = (const float*)d_in[10];
    const float* bs  = (const float*)d_in[11];
    float* out = (float*)d_out;

    const int* srcArr = ei;
    const int* dstArr = ei + N_EDGES;

    // workspace layout (~116 MB)
    char* w = (char*)d_ws;
    size_t off = 0;
    f16* wtbase = (f16*)(w + off); off += 5 * 65536 * 2;            // q,k,v,s,e transposed
    f16* wef16  = (f16*)(w + off); off += 65536 * 2;                // We row-major f16
    f16* qf = (f16*)(w + off); off += (size_t)N_NODES * 256 * 2;
    f16* kf = (f16*)(w + off); off += (size_t)N_NODES * 256 * 2;
    f16* vf = (f16*)(w + off); off += (size_t)N_NODES * 256 * 2;
    f16* G  = (f16*)(w + off); off += (size_t)N_NODES * 2048 * 2;   // G, then zhat (reused)
    int* deg    = (int*)(w + off); off += 80016;
    int* rowptr = (int*)(w + off); off += 80016;
    int* cursor = (int*)(w + off); off += 80016;
    int* eids   = (int*)(w + off); off += (size_t)N_EDGES * 4;
    int* srcs   = (int*)(w + off); off += (size_t)N_EDGES * 4;
    float* biasAll = (float*)(w + off); off += 4 * 256 * 4;
    (void)ws_size; (void)n_in; (void)in_sizes; (void)out_size;

    // prep: weight transposes + We f16 + bias pack + deg zero
    prep_all<<<1540 + (N_NODES + 255) / 256, 256, 0, stream>>>(
        Wq, Wk, Wv, Ws, We, bq, bk, bv, bs, wtbase, wef16, biasAll, deg);

    // CSR build
    count_deg<<<(N_EDGES + 255) / 256, 256, 0, stream>>>(dstArr, deg);
    scan_deg<<<1, 1024, 0, stream>>>(deg, rowptr, cursor);
    scatter_edges<<<(N_EDGES + 255) / 256, 256, 0, stream>>>(srcArr, dstArr, cursor, eids, srcs);

    // node GEMMs: q,k,v,skip
    dim3 gnode((N_NODES + 127) / 128, 8);
    gemm_qkvs<<<gnode, 512, 0, stream>>>(x, wtbase, biasAll, qf, out);

    // G = per-(node,head) 256-d logit vectors
    dim3 gg((N_NODES + 63) / 64, 8);
    gemm_g<<<gg, 256, 0, stream>>>(qf, wef16, G);

    // fused attention aggregate (streams ea once; overwrites G with zhat)
    aggregate3<<<(N_NODES + 3) / 4, 256, 0, stream>>>(
        qf, kf, vf, G, ea, eids, srcs, rowptr, out);

    // out += zhat_h @ We (per head)
    dim3 gz((N_NODES + 127) / 128, 8);
    gemm_z2<<<gz, 512, 0, stream>>>(G, wtbase + 4 * 65536, out);
}